// Round 10
// baseline (1441.050 us; speedup 1.0000x reference)
//
#include <hip/hip_runtime.h>
#include <hip/hip_bf16.h>
#include <stdint.h>

#define TT 4096
#define HH 4096
#define FF 14336
#define NCAT (2 * FF)   // 28672

typedef __attribute__((ext_vector_type(8))) short bf16x8;
typedef __attribute__((ext_vector_type(4))) float f32x4;
typedef __attribute__((ext_vector_type(16))) float f32x16;

__device__ __forceinline__ unsigned short f32_to_bf16(float f) {
    union { float f; unsigned int u; } v; v.f = f;
    unsigned int r = v.u + 0x7FFFu + ((v.u >> 16) & 1u);  // RNE
    return (unsigned short)(r >> 16);
}

#define GLOAD16(g, l)                                                          \
    __builtin_amdgcn_global_load_lds(                                          \
        (const __attribute__((address_space(1))) void*)(g),                    \
        (__attribute__((address_space(3))) void*)(l), 16, 0, 0)

// ---------------- convert fp32 -> bf16, same layout ----------------
__global__ void cvt_lin(const float* __restrict__ in,
                        unsigned short* __restrict__ out, long n4) {
    long stride = (long)gridDim.x * blockDim.x;
    for (long i = (long)blockIdx.x * blockDim.x + threadIdx.x; i < n4; i += stride) {
        float4 v = *(const float4*)(in + i * 4);
        ushort4 o;
        o.x = f32_to_bf16(v.x); o.y = f32_to_bf16(v.y);
        o.z = f32_to_bf16(v.z); o.w = f32_to_bf16(v.w);
        *(ushort4*)(out + i * 4) = o;
    }
}

// ---- convert + transpose + interleave: in [H][F] fp32 -> wcat rows bf16 ----
// 32-col granularity for 32x32 MFMA: f-col f -> wcat row ((f>>5)<<6)+(f&31)+off
// (off=0 gate, 32 up): each 64-row group of wcat = [gate f-block | up f-block].
__global__ void cvt_tri(const float* __restrict__ in,
                        unsigned short* __restrict__ out, int off) {
    __shared__ float tile[64][65];
    int bh = blockIdx.x & 63;   // H/64 = 64
    int bf = blockIdx.x >> 6;   // F/64 = 224
    int t = threadIdx.x;
    int r16 = t >> 4;           // 0..15
    int c4 = (t & 15) * 4;      // 0..60
#pragma unroll
    for (int it = 0; it < 4; ++it) {
        int h = r16 + it * 16;
        float4 v = *(const float4*)(in + (size_t)(bh * 64 + h) * FF + bf * 64 + c4);
        tile[h][c4 + 0] = v.x; tile[h][c4 + 1] = v.y;
        tile[h][c4 + 2] = v.z; tile[h][c4 + 3] = v.w;
    }
    __syncthreads();
#pragma unroll
    for (int it = 0; it < 4; ++it) {
        int f = r16 + it * 16;
        int fg = bf * 64 + f;
        int row_out = ((fg >> 5) << 6) + (fg & 31) + off;
        ushort4 o;
        o.x = f32_to_bf16(tile[c4 + 0][f]);
        o.y = f32_to_bf16(tile[c4 + 1][f]);
        o.z = f32_to_bf16(tile[c4 + 2][f]);
        o.w = f32_to_bf16(tile[c4 + 3][f]);
        *(ushort4*)(out + (size_t)row_out * HH + bh * 64 + c4) = o;
    }
}

// =================== 8-phase 256x256 GEMM core (BK=64, 8 waves) ============
// r10: MFMA shape 32x32x16 (4096 FLOP/busy-cyc vs 3413 for 16x16x32); same
// LDS bytes (24 ds_read_b128/wave/K-step, 8/4/8/4), same acc size (8xf32x16
// = 128 AGPR), same held frags (af 2x4 + bf 4 + bf 4 = 64 VGPR).
// A-frag: row=lane&31, k=(lane>>5)*8+reg.  B-frag: col=lane&31, same k.
// C/D: col=lane&31, row=(reg&3)+8*(reg>>2)+4*(lane>>5)  [m74/m101].
// LDS: A slots smem[0..64K): [2buf][2slot][128][64]b16; B at +64K.
// Swizzle byte ^= ((row&6)<<4) via pre-swizzled gload SOURCE + XOR on read.
// Snake (mq0,nq0)->(0,1)->(1,1)->(1,0); bfA (B0) resident across K-step,
// prefetched for the next K-step in ph4 (after VMC8).
// Stage map (own buf, tile t+2): ph2<-A0+B0, ph3<-B1, ph4<-A1; vmcnt(8) at
// K-step end drains the buffer read next.  c=1 stage offset = c=0 + 256*LD
// bytes (compile-time) -> only oA[2]/oB[2] live (saves 4 VGPRs vs r9; r9's
// 129MB WRITE_SIZE = ~4-reg spill, ideal is 114.7MB).

#define STG_A(BUF, SLOT, T) do {                                               \
    char* d_ = (char*)smem + (((BUF)*2 + (SLOT)) << 14) + tid * 16;            \
    GLOAD16(Abase + ((size_t)oA[SLOT] + (size_t)(T) * 128), d_);               \
    GLOAD16(Abase + ((size_t)oA[SLOT] + CA + (size_t)(T) * 128), d_ + 8192);   \
  } while (0)

#define STG_B(BUF, SLOT, T) do {                                               \
    char* d_ = (char*)smem + 65536 + (((BUF)*2 + (SLOT)) << 14) + tid * 16;    \
    GLOAD16(Bbase + ((size_t)oB[SLOT] + (size_t)(T) * 128), d_);               \
    GLOAD16(Bbase + ((size_t)oB[SLOT] + CB + (size_t)(T) * 128), d_ + 8192);   \
  } while (0)

#define READ_A(DST, BUF, MQ) do {                                              \
    const char* pA_ = (const char*)smem + (((BUF)*2 + (MQ)) << 14);            \
    _Pragma("unroll") for (int mb_ = 0; mb_ < 2; ++mb_)                        \
    _Pragma("unroll") for (int ks_ = 0; ks_ < 4; ++ks_)                        \
      DST[mb_][ks_] = *(const bf16x8*)(pA_ + ((wr*64 + mb_*32 + r31) << 7)     \
                                           + (((ks_ << 5) ^ lmask) + kh16));   \
  } while (0)

#define READ_B(DST, BUF, NQ) do {                                              \
    const char* pB_ = (const char*)smem + 65536 + (((BUF)*2 + (NQ)) << 14);    \
    _Pragma("unroll") for (int ks_ = 0; ks_ < 4; ++ks_)                        \
      DST[ks_] = *(const bf16x8*)(pB_ + ((wc*32 + r31) << 7)                   \
                                      + (((ks_ << 5) ^ lmask) + kh16));        \
  } while (0)

#define MFMA_Q(MQ, NQ, AF, BF)                                                 \
    _Pragma("unroll") for (int ks_ = 0; ks_ < 4; ++ks_)                        \
    _Pragma("unroll") for (int mb_ = 0; mb_ < 2; ++mb_)                        \
      acc[MQ][mb_][NQ] = __builtin_amdgcn_mfma_f32_32x32x16_bf16(              \
          AF[mb_][ks_], BF[ks_], acc[MQ][mb_][NQ], 0, 0, 0)

#define BAR do {                                                               \
    asm volatile("" ::: "memory");                                             \
    __builtin_amdgcn_s_barrier();                                              \
    asm volatile("" ::: "memory");                                             \
  } while (0)

#define VMC8 asm volatile("s_waitcnt vmcnt(8)" ::: "memory")
#define VMC0 asm volatile("s_waitcnt vmcnt(0)" ::: "memory")

#define PHX(READS, STAGES, MQ, NQ, AF, BF, FENCE, POST) do {                   \
    READS;                                                                     \
    STAGES;                                                                    \
    __builtin_amdgcn_s_setprio(1);                                             \
    MFMA_Q(MQ, NQ, AF, BF);                                                    \
    __builtin_amdgcn_s_setprio(0);                                             \
    FENCE;                                                                     \
    POST;                                                                      \
    BAR;                                                                       \
  } while (0)

#define PH(READS, STAGES, MQ, NQ, AF, BF, FENCE)                               \
    PHX(READS, STAGES, MQ, NQ, AF, BF, FENCE, )

// One K-step (BK=64) on buffer BUF (other OB); stages own tile TS = t+2.
#define HALF_STG(BUF, OB, TS)                                                  \
    PH(READ_A(af, BUF, 0), , 0, 0, af, bfA, );                                 \
    PH(READ_B(bfB, BUF, 1), STG_A(BUF, 0, TS); STG_B(BUF, 0, TS), 0, 1, af, bfB, ); \
    PH(READ_A(af, BUF, 1), STG_B(BUF, 1, TS), 1, 1, af, bfB, );                \
    PHX(, STG_A(BUF, 1, TS), 1, 0, af, bfA, VMC8, READ_B(bfA, OB, 0));

#define HALF_T1(BUF, OB)                                                       \
    PH(READ_A(af, BUF, 0), , 0, 0, af, bfA, );                                 \
    PH(READ_B(bfB, BUF, 1), , 0, 1, af, bfB, );                                \
    PH(READ_A(af, BUF, 1), , 1, 1, af, bfB, );                                 \
    PHX(, , 1, 0, af, bfA, VMC0, READ_B(bfA, OB, 0));

#define HALF_T2(BUF)                                                           \
    PH(READ_A(af, BUF, 0), , 0, 0, af, bfA, );                                 \
    PH(READ_B(bfB, BUF, 1), , 0, 1, af, bfB, );                                \
    PH(READ_A(af, BUF, 1), , 1, 1, af, bfB, );                                 \
    PHX(, , 1, 0, af, bfA, , );

#define GEMM8_CORE(A_, LDA_, B_, LDB_, NT_)                                    \
  extern __shared__ char smem[];                                               \
  const char* const Abase = (const char*)(A_);                                 \
  const char* const Bbase = (const char*)(B_);                                 \
  const size_t CA = (size_t)(LDA_) * 256;                                      \
  const size_t CB = (size_t)(LDB_) * 256;                                      \
  const int tid = threadIdx.x;                                                 \
  const int lane = tid & 63;                                                   \
  const int wid = tid >> 6;                                                    \
  const int wr = wid >> 2;                                                     \
  const int wc = wid & 3;                                                      \
  const int r31 = lane & 31;                                                   \
  const int kh16 = ((lane >> 5) << 4);                                         \
  const int lmask = (lane & 6) << 4;                                           \
  f32x16 acc[2][2][2];                                                         \
  _Pragma("unroll") for (int a_ = 0; a_ < 2; ++a_)                             \
  _Pragma("unroll") for (int b_ = 0; b_ < 2; ++b_)                             \
  _Pragma("unroll") for (int c_ = 0; c_ < 2; ++c_)                             \
  _Pragma("unroll") for (int e_ = 0; e_ < 16; ++e_)                            \
    acc[a_][b_][c_][e_] = 0.f;                                                 \
  bf16x8 af[2][4], bfA[4], bfB[4];                                             \
  unsigned int oA[2], oB[2];                                                   \
  {                                                                            \
    int d_ = tid * 16;                                                         \
    int p_ = d_ ^ (((d_ >> 8) & 3) << 5);                                      \
    int prow = p_ >> 7, pcol = (p_ & 127) >> 1;                                \
    _Pragma("unroll") for (int s_ = 0; s_ < 2; ++s_) {                         \
      int grA = m0 + s_ * 64 + (prow & 63);                                    \
      oA[s_] = (unsigned)((size_t)grA * (LDA_) + pcol) * 2u;                   \
      int grB = n0 + (prow >> 5) * 64 + s_ * 32 + (prow & 31);                 \
      oB[s_] = (unsigned)((size_t)grB * (LDB_) + pcol) * 2u;                   \
    }                                                                          \
  }                                                                            \
  /* prologue: both buffers' 4 slots (16 gloads); drain buf0's 8; preread */   \
  STG_A(0, 0, 0); STG_B(0, 0, 0); STG_B(0, 1, 0); STG_A(0, 1, 0);              \
  STG_A(1, 0, 1); STG_B(1, 0, 1); STG_B(1, 1, 1); STG_A(1, 1, 1);              \
  VMC8;                                                                        \
  __builtin_amdgcn_s_barrier();                                                \
  asm volatile("" ::: "memory");                                               \
  READ_B(bfA, 0, 0);                                                           \
  const int niter = (NT_) / 2;                                                 \
  for (int I = 0; I < niter - 1; ++I) {                                        \
    HALF_STG(0, 1, 2 * I + 2)                                                  \
    HALF_STG(1, 0, 2 * I + 3)                                                  \
  }                                                                            \
  HALF_T1(0, 1)                                                                \
  HALF_T2(1)

// ---------------- GEMM1: acc = Xb @ Wcat^T, fused SwiGLU epilogue ----------
__global__ __launch_bounds__(512)
__attribute__((amdgpu_waves_per_eu(1, 2))) void gemm_swiglu(
    const unsigned short* __restrict__ Xb,
    const unsigned short* __restrict__ Wcat,
    unsigned short* __restrict__ Act) {
    const int NWG = (TT / 256) * (NCAT / 256);  // 16*112 = 1792
    int lid = (blockIdx.x & 7) * (NWG / 8) + (blockIdx.x >> 3);
    const int m0 = (lid & 15) * 256;   // tm fast: weight panel reused across XCD chunk
    const int n0 = (lid >> 4) * 256;

    GEMM8_CORE(Xb, HH, Wcat, HH, HH / 64)

    const int col32 = lane & 31;
    const int rb = (lane >> 5) * 4;
#pragma unroll
    for (int mq = 0; mq < 2; ++mq)
#pragma unroll
        for (int mb = 0; mb < 2; ++mb) {
            f32x16 g16 = acc[mq][mb][0];
            f32x16 u16 = acc[mq][mb][1];
            int f = (n0 >> 1) + wc * 32 + col32;
            int row0 = m0 + wr * 128 + mq * 64 + mb * 32 + rb;
#pragma unroll
            for (int reg = 0; reg < 16; ++reg) {
                int row = row0 + (reg & 3) + 8 * (reg >> 2);
                float g = g16[reg], u = u16[reg];
                float s = g * u / (1.0f + __expf(-g));
                Act[(size_t)row * FF + f] = f32_to_bf16(s);
            }
        }
}

// ---------------- GEMM2: Out = Act @ W2b^T ----------------------------------
__global__ __launch_bounds__(512)
__attribute__((amdgpu_waves_per_eu(1, 2))) void gemm_down(
    const unsigned short* __restrict__ Act,
    const unsigned short* __restrict__ W2b,
    float* __restrict__ Out) {
    const int NWG = (TT / 256) * (HH / 256);  // 16*16 = 256
    int lid = (blockIdx.x & 7) * (NWG / 8) + (blockIdx.x >> 3);
    const int m0 = (lid & 15) * 256;
    const int n0 = (lid >> 4) * 256;

    GEMM8_CORE(Act, FF, W2b, FF, FF / 64)

    const int col32 = lane & 31;
    const int rb = (lane >> 5) * 4;
#pragma unroll
    for (int mq = 0; mq < 2; ++mq)
#pragma unroll
        for (int mb = 0; mb < 2; ++mb)
#pragma unroll
            for (int nq = 0; nq < 2; ++nq) {
                f32x16 v = acc[mq][mb][nq];
                int col = n0 + wc * 64 + nq * 32 + col32;
                int row0 = m0 + wr * 128 + mq * 64 + mb * 32 + rb;
#pragma unroll
                for (int reg = 0; reg < 16; ++reg) {
                    int row = row0 + (reg & 3) + 8 * (reg >> 2);
                    Out[(size_t)row * HH + col] = v[reg];
                }
            }
}

extern "C" void kernel_launch(void* const* d_in, const int* in_sizes, int n_in,
                              void* d_out, int out_size, void* d_ws, size_t ws_size,
                              hipStream_t stream) {
    const float* x  = (const float*)d_in[0];
    const float* w1 = (const float*)d_in[1];
    const float* v1 = (const float*)d_in[2];
    const float* w2 = (const float*)d_in[3];
    float* out = (float*)d_out;

    unsigned short* xb   = (unsigned short*)d_ws;               // [T][H]
    unsigned short* wcat = xb + (size_t)TT * HH;                // [2F][H]
    unsigned short* w2b  = wcat + (size_t)NCAT * HH;            // [H][F]
    unsigned short* act  = w2b + (size_t)HH * FF;               // [T][F]

    hipFuncSetAttribute((const void*)gemm_swiglu,
                        hipFuncAttributeMaxDynamicSharedMemorySize, 131072);
    hipFuncSetAttribute((const void*)gemm_down,
                        hipFuncAttributeMaxDynamicSharedMemorySize, 131072);

    cvt_lin<<<2048, 256, 0, stream>>>(x, xb, (long)TT * HH / 4);
    cvt_lin<<<2048, 256, 0, stream>>>(w2, w2b, (long)HH * FF / 4);
    cvt_tri<<<(HH / 64) * (FF / 64), 256, 0, stream>>>(w1, wcat, 0);
    cvt_tri<<<(HH / 64) * (FF / 64), 256, 0, stream>>>(v1, wcat, 32);

    gemm_swiglu<<<(TT / 256) * (NCAT / 256), 512, 131072, stream>>>(xb, wcat, act);
    gemm_down<<<(TT / 256) * (HH / 256), 512, 131072, stream>>>(act, w2b, out);
}

// Round 11
// 1439.141 us; speedup vs baseline: 1.0013x; 1.0013x over previous
//
#include <hip/hip_runtime.h>
#include <hip/hip_bf16.h>
#include <stdint.h>

#define TT 4096
#define HH 4096
#define FF 14336
#define NCAT (2 * FF)   // 28672

typedef __attribute__((ext_vector_type(8))) short bf16x8;
typedef __attribute__((ext_vector_type(4))) float f32x4;
typedef __attribute__((ext_vector_type(16))) float f32x16;

__device__ __forceinline__ unsigned short f32_to_bf16(float f) {
    union { float f; unsigned int u; } v; v.f = f;
    unsigned int r = v.u + 0x7FFFu + ((v.u >> 16) & 1u);  // RNE
    return (unsigned short)(r >> 16);
}

#define GLOAD16(g, l)                                                          \
    __builtin_amdgcn_global_load_lds(                                          \
        (const __attribute__((address_space(1))) void*)(g),                    \
        (__attribute__((address_space(3))) void*)(l), 16, 0, 0)

// ---------------- convert fp32 -> bf16, same layout ----------------
__global__ void cvt_lin(const float* __restrict__ in,
                        unsigned short* __restrict__ out, long n4) {
    long stride = (long)gridDim.x * blockDim.x;
    for (long i = (long)blockIdx.x * blockDim.x + threadIdx.x; i < n4; i += stride) {
        float4 v = *(const float4*)(in + i * 4);
        ushort4 o;
        o.x = f32_to_bf16(v.x); o.y = f32_to_bf16(v.y);
        o.z = f32_to_bf16(v.z); o.w = f32_to_bf16(v.w);
        *(ushort4*)(out + i * 4) = o;
    }
}

// ---- convert + transpose + interleave: in [H][F] fp32 -> wcat rows bf16 ----
// 32-col granularity for 32x32 MFMA: f-col f -> wcat row ((f>>5)<<6)+(f&31)+off
// (off=0 gate, 32 up): each 64-row group of wcat = [gate f-block | up f-block].
__global__ void cvt_tri(const float* __restrict__ in,
                        unsigned short* __restrict__ out, int off) {
    __shared__ float tile[64][65];
    int bh = blockIdx.x & 63;   // H/64 = 64
    int bf = blockIdx.x >> 6;   // F/64 = 224
    int t = threadIdx.x;
    int r16 = t >> 4;           // 0..15
    int c4 = (t & 15) * 4;      // 0..60
#pragma unroll
    for (int it = 0; it < 4; ++it) {
        int h = r16 + it * 16;
        float4 v = *(const float4*)(in + (size_t)(bh * 64 + h) * FF + bf * 64 + c4);
        tile[h][c4 + 0] = v.x; tile[h][c4 + 1] = v.y;
        tile[h][c4 + 2] = v.z; tile[h][c4 + 3] = v.w;
    }
    __syncthreads();
#pragma unroll
    for (int it = 0; it < 4; ++it) {
        int f = r16 + it * 16;
        int fg = bf * 64 + f;
        int row_out = ((fg >> 5) << 6) + (fg & 31) + off;
        ushort4 o;
        o.x = f32_to_bf16(tile[c4 + 0][f]);
        o.y = f32_to_bf16(tile[c4 + 1][f]);
        o.z = f32_to_bf16(tile[c4 + 2][f]);
        o.w = f32_to_bf16(tile[c4 + 3][f]);
        *(ushort4*)(out + (size_t)row_out * HH + bh * 64 + c4) = o;
    }
}

// =================== 8-phase 256x256 GEMM core (BK=64, 8 waves) ============
// r11: 32x32x16 MFMA (r10) + 3-bit LDS swizzle byte ^= ((row&7)<<4).
// r10's 2-bit swizzle left read col bit4 = lane>>5 (constant per half-wave)
// -> 16 of 32 banks idle -> 8.8e7 conflicts.  3-bit form injects row bit0
// into col bit4: read col bits 4-6 = (b5^b0, ks0^b1, ks1^b2) -> all 8 chunk
// offsets per half-wave, 4 lanes each (the proven 16x16 structure).
// A-frag: row=lane&31, k=(lane>>5)*8+reg.  B-frag: col=lane&31, same k.
// C/D: col=lane&31, row=(reg&3)+8*(reg>>2)+4*(lane>>5)  [m74/m101, r10-verified].
// LDS: A slots smem[0..64K): [2buf][2slot][128][64]b16; B at +64K.
// Snake (mq0,nq0)->(0,1)->(1,1)->(1,0); bfA (B0) resident across K-step,
// prefetched for the next K-step in ph4 (after VMC8).
// Stage map (own buf, tile t+2): ph2<-A0+B0, ph3<-B1, ph4<-A1; vmcnt(8) at
// K-step end.  Reads/K-step 24 b128, balanced 8/4/8/4.  Held frags 64 VGPR;
// acc = 8 x f32x16 = 128 AGPR; arch cap 128 (no spill: WRITE_SIZE=114.7MB).

#define STG_A(BUF, SLOT, T) do {                                               \
    char* d_ = (char*)smem + (((BUF)*2 + (SLOT)) << 14) + tid * 16;            \
    GLOAD16(Abase + ((size_t)oA[SLOT] + (size_t)(T) * 128), d_);               \
    GLOAD16(Abase + ((size_t)oA[SLOT] + CA + (size_t)(T) * 128), d_ + 8192);   \
  } while (0)

#define STG_B(BUF, SLOT, T) do {                                               \
    char* d_ = (char*)smem + 65536 + (((BUF)*2 + (SLOT)) << 14) + tid * 16;    \
    GLOAD16(Bbase + ((size_t)oB[SLOT] + (size_t)(T) * 128), d_);               \
    GLOAD16(Bbase + ((size_t)oB[SLOT] + CB + (size_t)(T) * 128), d_ + 8192);   \
  } while (0)

#define READ_A(DST, BUF, MQ) do {                                              \
    const char* pA_ = (const char*)smem + (((BUF)*2 + (MQ)) << 14);            \
    _Pragma("unroll") for (int mb_ = 0; mb_ < 2; ++mb_)                        \
    _Pragma("unroll") for (int ks_ = 0; ks_ < 4; ++ks_)                        \
      DST[mb_][ks_] = *(const bf16x8*)(pA_ + ((wr*64 + mb_*32 + r31) << 7)     \
                                           + (((ks_ << 5) + kh16) ^ lmask));   \
  } while (0)

#define READ_B(DST, BUF, NQ) do {                                              \
    const char* pB_ = (const char*)smem + 65536 + (((BUF)*2 + (NQ)) << 14);    \
    _Pragma("unroll") for (int ks_ = 0; ks_ < 4; ++ks_)                        \
      DST[ks_] = *(const bf16x8*)(pB_ + ((wc*32 + r31) << 7)                   \
                                      + (((ks_ << 5) + kh16) ^ lmask));        \
  } while (0)

#define MFMA_Q(MQ, NQ, AF, BF)                                                 \
    _Pragma("unroll") for (int ks_ = 0; ks_ < 4; ++ks_)                        \
    _Pragma("unroll") for (int mb_ = 0; mb_ < 2; ++mb_)                        \
      acc[MQ][mb_][NQ] = __builtin_amdgcn_mfma_f32_32x32x16_bf16(              \
          AF[mb_][ks_], BF[ks_], acc[MQ][mb_][NQ], 0, 0, 0)

#define BAR do {                                                               \
    asm volatile("" ::: "memory");                                             \
    __builtin_amdgcn_s_barrier();                                              \
    asm volatile("" ::: "memory");                                             \
  } while (0)

#define VMC8 asm volatile("s_waitcnt vmcnt(8)" ::: "memory")
#define VMC0 asm volatile("s_waitcnt vmcnt(0)" ::: "memory")

#define PHX(READS, STAGES, MQ, NQ, AF, BF, FENCE, POST) do {                   \
    READS;                                                                     \
    STAGES;                                                                    \
    __builtin_amdgcn_s_setprio(1);                                             \
    MFMA_Q(MQ, NQ, AF, BF);                                                    \
    __builtin_amdgcn_s_setprio(0);                                             \
    FENCE;                                                                     \
    POST;                                                                      \
    BAR;                                                                       \
  } while (0)

#define PH(READS, STAGES, MQ, NQ, AF, BF, FENCE)                               \
    PHX(READS, STAGES, MQ, NQ, AF, BF, FENCE, )

// One K-step (BK=64) on buffer BUF (other OB); stages own tile TS = t+2.
#define HALF_STG(BUF, OB, TS)                                                  \
    PH(READ_A(af, BUF, 0), , 0, 0, af, bfA, );                                 \
    PH(READ_B(bfB, BUF, 1), STG_A(BUF, 0, TS); STG_B(BUF, 0, TS), 0, 1, af, bfB, ); \
    PH(READ_A(af, BUF, 1), STG_B(BUF, 1, TS), 1, 1, af, bfB, );                \
    PHX(, STG_A(BUF, 1, TS), 1, 0, af, bfA, VMC8, READ_B(bfA, OB, 0));

#define HALF_T1(BUF, OB)                                                       \
    PH(READ_A(af, BUF, 0), , 0, 0, af, bfA, );                                 \
    PH(READ_B(bfB, BUF, 1), , 0, 1, af, bfB, );                                \
    PH(READ_A(af, BUF, 1), , 1, 1, af, bfB, );                                 \
    PHX(, , 1, 0, af, bfA, VMC0, READ_B(bfA, OB, 0));

#define HALF_T2(BUF)                                                           \
    PH(READ_A(af, BUF, 0), , 0, 0, af, bfA, );                                 \
    PH(READ_B(bfB, BUF, 1), , 0, 1, af, bfB, );                                \
    PH(READ_A(af, BUF, 1), , 1, 1, af, bfB, );                                 \
    PHX(, , 1, 0, af, bfA, , );

#define GEMM8_CORE(A_, LDA_, B_, LDB_, NT_)                                    \
  extern __shared__ char smem[];                                               \
  const char* const Abase = (const char*)(A_);                                 \
  const char* const Bbase = (const char*)(B_);                                 \
  const size_t CA = (size_t)(LDA_) * 256;                                      \
  const size_t CB = (size_t)(LDB_) * 256;                                      \
  const int tid = threadIdx.x;                                                 \
  const int lane = tid & 63;                                                   \
  const int wid = tid >> 6;                                                    \
  const int wr = wid >> 2;                                                     \
  const int wc = wid & 3;                                                      \
  const int r31 = lane & 31;                                                   \
  const int kh16 = ((lane >> 5) << 4);                                         \
  const int lmask = (lane & 7) << 4;                                           \
  f32x16 acc[2][2][2];                                                         \
  _Pragma("unroll") for (int a_ = 0; a_ < 2; ++a_)                             \
  _Pragma("unroll") for (int b_ = 0; b_ < 2; ++b_)                             \
  _Pragma("unroll") for (int c_ = 0; c_ < 2; ++c_)                             \
  _Pragma("unroll") for (int e_ = 0; e_ < 16; ++e_)                            \
    acc[a_][b_][c_][e_] = 0.f;                                                 \
  bf16x8 af[2][4], bfA[4], bfB[4];                                             \
  unsigned int oA[2], oB[2];                                                   \
  {                                                                            \
    int d_ = tid * 16;                                                         \
    int p_ = d_ ^ (((d_ >> 7) & 7) << 4);                                      \
    int prow = p_ >> 7, pcol = (p_ & 127) >> 1;                                \
    _Pragma("unroll") for (int s_ = 0; s_ < 2; ++s_) {                         \
      int grA = m0 + s_ * 64 + (prow & 63);                                    \
      oA[s_] = (unsigned)((size_t)grA * (LDA_) + pcol) * 2u;                   \
      int grB = n0 + (prow >> 5) * 64 + s_ * 32 + (prow & 31);                 \
      oB[s_] = (unsigned)((size_t)grB * (LDB_) + pcol) * 2u;                   \
    }                                                                          \
  }                                                                            \
  /* prologue: both buffers' 4 slots (16 gloads); drain buf0's 8; preread */   \
  STG_A(0, 0, 0); STG_B(0, 0, 0); STG_B(0, 1, 0); STG_A(0, 1, 0);              \
  STG_A(1, 0, 1); STG_B(1, 0, 1); STG_B(1, 1, 1); STG_A(1, 1, 1);              \
  VMC8;                                                                        \
  __builtin_amdgcn_s_barrier();                                                \
  asm volatile("" ::: "memory");                                               \
  READ_B(bfA, 0, 0);                                                           \
  const int niter = (NT_) / 2;                                                 \
  for (int I = 0; I < niter - 1; ++I) {                                        \
    HALF_STG(0, 1, 2 * I + 2)                                                  \
    HALF_STG(1, 0, 2 * I + 3)                                                  \
  }                                                                            \
  HALF_T1(0, 1)                                                                \
  HALF_T2(1)

// ---------------- GEMM1: acc = Xb @ Wcat^T, fused SwiGLU epilogue ----------
__global__ __launch_bounds__(512)
__attribute__((amdgpu_waves_per_eu(1, 2))) void gemm_swiglu(
    const unsigned short* __restrict__ Xb,
    const unsigned short* __restrict__ Wcat,
    unsigned short* __restrict__ Act) {
    const int NWG = (TT / 256) * (NCAT / 256);  // 16*112 = 1792
    int lid = (blockIdx.x & 7) * (NWG / 8) + (blockIdx.x >> 3);
    const int m0 = (lid & 15) * 256;   // tm fast: weight panel reused across XCD chunk
    const int n0 = (lid >> 4) * 256;

    GEMM8_CORE(Xb, HH, Wcat, HH, HH / 64)

    const int col32 = lane & 31;
    const int rb = (lane >> 5) * 4;
#pragma unroll
    for (int mq = 0; mq < 2; ++mq)
#pragma unroll
        for (int mb = 0; mb < 2; ++mb) {
            f32x16 g16 = acc[mq][mb][0];
            f32x16 u16 = acc[mq][mb][1];
            int f = (n0 >> 1) + wc * 32 + col32;
            int row0 = m0 + wr * 128 + mq * 64 + mb * 32 + rb;
#pragma unroll
            for (int reg = 0; reg < 16; ++reg) {
                int row = row0 + (reg & 3) + 8 * (reg >> 2);
                float g = g16[reg], u = u16[reg];
                float s = g * u / (1.0f + __expf(-g));
                Act[(size_t)row * FF + f] = f32_to_bf16(s);
            }
        }
}

// ---------------- GEMM2: Out = Act @ W2b^T ----------------------------------
__global__ __launch_bounds__(512)
__attribute__((amdgpu_waves_per_eu(1, 2))) void gemm_down(
    const unsigned short* __restrict__ Act,
    const unsigned short* __restrict__ W2b,
    float* __restrict__ Out) {
    const int NWG = (TT / 256) * (HH / 256);  // 16*16 = 256
    int lid = (blockIdx.x & 7) * (NWG / 8) + (blockIdx.x >> 3);
    const int m0 = (lid & 15) * 256;
    const int n0 = (lid >> 4) * 256;

    GEMM8_CORE(Act, FF, W2b, FF, FF / 64)

    const int col32 = lane & 31;
    const int rb = (lane >> 5) * 4;
#pragma unroll
    for (int mq = 0; mq < 2; ++mq)
#pragma unroll
        for (int mb = 0; mb < 2; ++mb)
#pragma unroll
            for (int nq = 0; nq < 2; ++nq) {
                f32x16 v = acc[mq][mb][nq];
                int col = n0 + wc * 64 + nq * 32 + col32;
                int row0 = m0 + wr * 128 + mq * 64 + mb * 32 + rb;
#pragma unroll
                for (int reg = 0; reg < 16; ++reg) {
                    int row = row0 + (reg & 3) + 8 * (reg >> 2);
                    Out[(size_t)row * HH + col] = v[reg];
                }
            }
}

extern "C" void kernel_launch(void* const* d_in, const int* in_sizes, int n_in,
                              void* d_out, int out_size, void* d_ws, size_t ws_size,
                              hipStream_t stream) {
    const float* x  = (const float*)d_in[0];
    const float* w1 = (const float*)d_in[1];
    const float* v1 = (const float*)d_in[2];
    const float* w2 = (const float*)d_in[3];
    float* out = (float*)d_out;

    unsigned short* xb   = (unsigned short*)d_ws;               // [T][H]
    unsigned short* wcat = xb + (size_t)TT * HH;                // [2F][H]
    unsigned short* w2b  = wcat + (size_t)NCAT * HH;            // [H][F]
    unsigned short* act  = w2b + (size_t)HH * FF;               // [T][F]

    hipFuncSetAttribute((const void*)gemm_swiglu,
                        hipFuncAttributeMaxDynamicSharedMemorySize, 131072);
    hipFuncSetAttribute((const void*)gemm_down,
                        hipFuncAttributeMaxDynamicSharedMemorySize, 131072);

    cvt_lin<<<2048, 256, 0, stream>>>(x, xb, (long)TT * HH / 4);
    cvt_lin<<<2048, 256, 0, stream>>>(w2, w2b, (long)HH * FF / 4);
    cvt_tri<<<(HH / 64) * (FF / 64), 256, 0, stream>>>(w1, wcat, 0);
    cvt_tri<<<(HH / 64) * (FF / 64), 256, 0, stream>>>(v1, wcat, 32);

    gemm_swiglu<<<(TT / 256) * (NCAT / 256), 512, 131072, stream>>>(xb, wcat, act);
    gemm_down<<<(TT / 256) * (HH / 256), 512, 131072, stream>>>(act, w2b, out);
}

// Round 12
// 1286.024 us; speedup vs baseline: 1.1205x; 1.1191x over previous
//
#include <hip/hip_runtime.h>
#include <hip/hip_bf16.h>
#include <stdint.h>

#define TT 4096
#define HH 4096
#define FF 14336
#define NCAT (2 * FF)   // 28672

typedef __attribute__((ext_vector_type(8))) short bf16x8;
typedef __attribute__((ext_vector_type(4))) float f32x4;

__device__ __forceinline__ unsigned short f32_to_bf16(float f) {
    union { float f; unsigned int u; } v; v.f = f;
    unsigned int r = v.u + 0x7FFFu + ((v.u >> 16) & 1u);  // RNE
    return (unsigned short)(r >> 16);
}

#define GLOAD16(g, l)                                                          \
    __builtin_amdgcn_global_load_lds(                                          \
        (const __attribute__((address_space(1))) void*)(g),                    \
        (__attribute__((address_space(3))) void*)(l), 16, 0, 0)

// ---------------- convert fp32 -> bf16, same layout ----------------
__global__ void cvt_lin(const float* __restrict__ in,
                        unsigned short* __restrict__ out, long n4) {
    long stride = (long)gridDim.x * blockDim.x;
    for (long i = (long)blockIdx.x * blockDim.x + threadIdx.x; i < n4; i += stride) {
        float4 v = *(const float4*)(in + i * 4);
        ushort4 o;
        o.x = f32_to_bf16(v.x); o.y = f32_to_bf16(v.y);
        o.z = f32_to_bf16(v.z); o.w = f32_to_bf16(v.w);
        *(ushort4*)(out + i * 4) = o;
    }
}

// ---- convert + transpose + interleave: in [H][F] fp32 -> wcat rows bf16 ----
// f-column f of `in` goes to wcat row ((f>>4)<<5) + (f&15) + off (off=0 gate,
// 16 up): 16-col interleave matching the 16x16 MFMA epilogue pairing.
__global__ void cvt_tri(const float* __restrict__ in,
                        unsigned short* __restrict__ out, int off) {
    __shared__ float tile[64][65];
    int bh = blockIdx.x & 63;   // H/64 = 64
    int bf = blockIdx.x >> 6;   // F/64 = 224
    int t = threadIdx.x;
    int r16 = t >> 4;           // 0..15
    int c4 = (t & 15) * 4;      // 0..60
#pragma unroll
    for (int it = 0; it < 4; ++it) {
        int h = r16 + it * 16;
        float4 v = *(const float4*)(in + (size_t)(bh * 64 + h) * FF + bf * 64 + c4);
        tile[h][c4 + 0] = v.x; tile[h][c4 + 1] = v.y;
        tile[h][c4 + 2] = v.z; tile[h][c4 + 3] = v.w;
    }
    __syncthreads();
#pragma unroll
    for (int it = 0; it < 4; ++it) {
        int f = r16 + it * 16;
        int fg = bf * 64 + f;
        int row_out = ((fg >> 4) << 5) + (fg & 15) + off;
        ushort4 o;
        o.x = f32_to_bf16(tile[c4 + 0][f]);
        o.y = f32_to_bf16(tile[c4 + 1][f]);
        o.z = f32_to_bf16(tile[c4 + 2][f]);
        o.w = f32_to_bf16(tile[c4 + 3][f]);
        *(ushort4*)(out + (size_t)row_out * HH + bh * 64 + c4) = o;
    }
}

// =================== 8-phase 256x256 GEMM core (BK=64, 8 waves) ============
// r12 = r9's proven 16x16x32 core (0 bank conflicts, MfmaUtil 57) with two
// validated fixes:
//  (a) compile-time CA/CB second-gload offsets (r10: kills r9's 4-reg spill,
//      WRITE_SIZE 129 -> 114.7 MB);
//  (b) NO XCD chunk swizzle: natural dispatch + tm-fast lid gives all XCDs a
//      shared 32-n-column W window (~64MB) + X (32MB) resident in L3 -> W
//      read once.  The swizzle made 8 disjoint 28MB W streams + X ~ 256MB
//      = L3 thrash (r9-r11 FETCH 1.04GB vs 267MB ideal).
// [32x32x16 attempted r10/r11: +20% MFMA-rate but fixed 4 conflict-cyc per
//  ds_read_b128 from the 32-row-span read pattern, swizzle-invariant. Net
//  loss; reverted.]
// Schedule (r9): hold af(32, in-place) + bfA(16, B0 resident) + bfB(16).
// 24 ds_reads/K-step balanced 8/4/8/4 (ph4 prefetches next K-step's B0).
// Snake (m0n0)->(m0n1)->(m1n1)->(m1n0).
// Stage map (own buf, tile t+2): ph2<-A0+B0, ph3<-B1, ph4<-A1; vmcnt(8) at
// K-step end.  Swizzle byte ^= ((row&6)<<4) via pre-swizzled gload SOURCE +
// XOR on ds_read (LDS linear; proven conflict-free for this 16-row pattern).

#define STG_A(BUF, SLOT, T) do {                                               \
    char* d_ = (char*)smem + (((BUF)*2 + (SLOT)) << 14) + tid * 16;            \
    GLOAD16(Abase + ((size_t)oA[SLOT] + (size_t)(T) * 128), d_);               \
    GLOAD16(Abase + ((size_t)oA[SLOT] + CA + (size_t)(T) * 128), d_ + 8192);   \
  } while (0)

#define STG_B(BUF, SLOT, T) do {                                               \
    char* d_ = (char*)smem + 65536 + (((BUF)*2 + (SLOT)) << 14) + tid * 16;    \
    GLOAD16(Bbase + ((size_t)oB[SLOT] + (size_t)(T) * 128), d_);               \
    GLOAD16(Bbase + ((size_t)oB[SLOT] + CB + (size_t)(T) * 128), d_ + 8192);   \
  } while (0)

#define READ_A(DST, BUF, MQ) do {                                              \
    const char* pA_ = (const char*)smem + (((BUF)*2 + (MQ)) << 14);            \
    _Pragma("unroll") for (int i_ = 0; i_ < 4; ++i_)                           \
    _Pragma("unroll") for (int k_ = 0; k_ < 2; ++k_)                           \
      DST[i_][k_] = *(const bf16x8*)(pA_ + ((((wr*64 + i_*16 + fr) << 7) + k_*64 + kg2) ^ lmask)); \
  } while (0)

#define READ_B(DST, BUF, NQ) do {                                              \
    const char* pB_ = (const char*)smem + 65536 + (((BUF)*2 + (NQ)) << 14);    \
    _Pragma("unroll") for (int j_ = 0; j_ < 2; ++j_)                           \
    _Pragma("unroll") for (int k_ = 0; k_ < 2; ++k_)                           \
      DST[j_][k_] = *(const bf16x8*)(pB_ + ((((wc*32 + j_*16 + fr) << 7) + k_*64 + kg2) ^ lmask)); \
  } while (0)

#define MFMA_Q(MQ, NQ, AF, BF)                                                 \
    _Pragma("unroll") for (int i_ = 0; i_ < 4; ++i_)                           \
    _Pragma("unroll") for (int j_ = 0; j_ < 2; ++j_)                           \
    _Pragma("unroll") for (int k_ = 0; k_ < 2; ++k_)                           \
      acc[MQ][i_][NQ][j_] = __builtin_amdgcn_mfma_f32_16x16x32_bf16(           \
          AF[i_][k_], BF[j_][k_], acc[MQ][i_][NQ][j_], 0, 0, 0)

#define BAR do {                                                               \
    asm volatile("" ::: "memory");                                             \
    __builtin_amdgcn_s_barrier();                                              \
    asm volatile("" ::: "memory");                                             \
  } while (0)

#define VMC8 asm volatile("s_waitcnt vmcnt(8)" ::: "memory")
#define VMC0 asm volatile("s_waitcnt vmcnt(0)" ::: "memory")

#define PHX(READS, STAGES, MQ, NQ, AF, BF, FENCE, POST) do {                   \
    READS;                                                                     \
    STAGES;                                                                    \
    __builtin_amdgcn_s_setprio(1);                                             \
    MFMA_Q(MQ, NQ, AF, BF);                                                    \
    __builtin_amdgcn_s_setprio(0);                                             \
    FENCE;                                                                     \
    POST;                                                                      \
    BAR;                                                                       \
  } while (0)

#define PH(READS, STAGES, MQ, NQ, AF, BF, FENCE)                               \
    PHX(READS, STAGES, MQ, NQ, AF, BF, FENCE, )

// One K-step (BK=64) on buffer BUF (other OB); stages own tile TS = t+2.
#define HALF_STG(BUF, OB, TS)                                                  \
    PH(READ_A(af, BUF, 0), , 0, 0, af, bfA, );                                 \
    PH(READ_B(bfB, BUF, 1), STG_A(BUF, 0, TS); STG_B(BUF, 0, TS), 0, 1, af, bfB, ); \
    PH(READ_A(af, BUF, 1), STG_B(BUF, 1, TS), 1, 1, af, bfB, );                \
    PHX(, STG_A(BUF, 1, TS), 1, 0, af, bfA, VMC8, READ_B(bfA, OB, 0));

#define HALF_T1(BUF, OB)                                                       \
    PH(READ_A(af, BUF, 0), , 0, 0, af, bfA, );                                 \
    PH(READ_B(bfB, BUF, 1), , 0, 1, af, bfB, );                                \
    PH(READ_A(af, BUF, 1), , 1, 1, af, bfB, );                                 \
    PHX(, , 1, 0, af, bfA, VMC0, READ_B(bfA, OB, 0));

#define HALF_T2(BUF)                                                           \
    PH(READ_A(af, BUF, 0), , 0, 0, af, bfA, );                                 \
    PH(READ_B(bfB, BUF, 1), , 0, 1, af, bfB, );                                \
    PH(READ_A(af, BUF, 1), , 1, 1, af, bfB, );                                 \
    PHX(, , 1, 0, af, bfA, , );

#define GEMM8_CORE(A_, LDA_, B_, LDB_, NT_)                                    \
  extern __shared__ char smem[];                                               \
  const char* const Abase = (const char*)(A_);                                 \
  const char* const Bbase = (const char*)(B_);                                 \
  const size_t CA = (size_t)(LDA_) * 256;                                      \
  const size_t CB = (size_t)(LDB_) * 256;                                      \
  const int tid = threadIdx.x;                                                 \
  const int lane = tid & 63;                                                   \
  const int wid = tid >> 6;                                                    \
  const int wr = wid >> 2;                                                     \
  const int wc = wid & 3;                                                      \
  const int fr = lane & 15;                                                    \
  const int kg2 = ((lane >> 4) & 3) << 4;                                      \
  const int lmask = (fr & 6) << 4;                                             \
  f32x4 acc[2][4][2][2];                                                       \
  _Pragma("unroll") for (int a_ = 0; a_ < 2; ++a_)                             \
  _Pragma("unroll") for (int b_ = 0; b_ < 4; ++b_)                             \
  _Pragma("unroll") for (int c_ = 0; c_ < 2; ++c_)                             \
  _Pragma("unroll") for (int d_ = 0; d_ < 2; ++d_)                             \
    acc[a_][b_][c_][d_] = (f32x4){0.f, 0.f, 0.f, 0.f};                         \
  bf16x8 af[4][2], bfA[2][2], bfB[2][2];                                       \
  unsigned int oA[2], oB[2];                                                   \
  {                                                                            \
    int d_ = tid * 16;                                                         \
    int p_ = d_ ^ (((d_ >> 8) & 3) << 5);                                      \
    int prow = p_ >> 7, pcol = (p_ & 127) >> 1;                                \
    _Pragma("unroll") for (int s_ = 0; s_ < 2; ++s_) {                         \
      int grA = m0 + s_ * 64 + (prow & 63);                                    \
      oA[s_] = (unsigned)((size_t)grA * (LDA_) + pcol) * 2u;                   \
      int grB = n0 + (prow >> 5) * 64 + s_ * 32 + (prow & 31);                 \
      oB[s_] = (unsigned)((size_t)grB * (LDB_) + pcol) * 2u;                   \
    }                                                                          \
  }                                                                            \
  /* prologue: both buffers' 4 slots (16 gloads); drain buf0's 8; preread */   \
  STG_A(0, 0, 0); STG_B(0, 0, 0); STG_B(0, 1, 0); STG_A(0, 1, 0);              \
  STG_A(1, 0, 1); STG_B(1, 0, 1); STG_B(1, 1, 1); STG_A(1, 1, 1);              \
  VMC8;                                                                        \
  __builtin_amdgcn_s_barrier();                                                \
  asm volatile("" ::: "memory");                                               \
  READ_B(bfA, 0, 0);                                                           \
  const int niter = (NT_) / 2;                                                 \
  for (int I = 0; I < niter - 1; ++I) {                                        \
    HALF_STG(0, 1, 2 * I + 2)                                                  \
    HALF_STG(1, 0, 2 * I + 3)                                                  \
  }                                                                            \
  HALF_T1(0, 1)                                                                \
  HALF_T2(1)

// ---------------- GEMM1: acc = Xb @ Wcat^T, fused SwiGLU epilogue ----------
__global__ __launch_bounds__(512)
__attribute__((amdgpu_waves_per_eu(1, 2))) void gemm_swiglu(
    const unsigned short* __restrict__ Xb,
    const unsigned short* __restrict__ Wcat,
    unsigned short* __restrict__ Act) {
    // tm-fast, NO XCD swizzle: consecutive bids share one n-column, spread
    // across XCDs by natural round-robin -> shared W window in L3.
    int lid = blockIdx.x;
    const int m0 = (lid & 15) * 256;
    const int n0 = (lid >> 4) * 256;

    GEMM8_CORE(Xb, HH, Wcat, HH, HH / 64)

    const int dm = ((lane >> 4) & 3) * 4;
    const int dn = lane & 15;
#pragma unroll
    for (int mq = 0; mq < 2; ++mq)
#pragma unroll
        for (int i = 0; i < 4; ++i)
#pragma unroll
            for (int nq = 0; nq < 2; ++nq) {
                int rowb = m0 + wr * 128 + mq * 64 + i * 16 + dm;
                int col = (n0 + wc * 64 + nq * 32) / 2 + dn;
                f32x4 g4 = acc[mq][i][nq][0];
                f32x4 u4 = acc[mq][i][nq][1];
#pragma unroll
                for (int r = 0; r < 4; ++r) {
                    float g = g4[r], u = u4[r];
                    float s = g * u / (1.0f + __expf(-g));
                    Act[(size_t)(rowb + r) * FF + col] = f32_to_bf16(s);
                }
            }
}

// ---------------- GEMM2: Out = Act @ W2b^T ----------------------------------
__global__ __launch_bounds__(512)
__attribute__((amdgpu_waves_per_eu(1, 2))) void gemm_down(
    const unsigned short* __restrict__ Act,
    const unsigned short* __restrict__ W2b,
    float* __restrict__ Out) {
    int lid = blockIdx.x;
    const int m0 = (lid & 15) * 256;
    const int n0 = (lid >> 4) * 256;

    GEMM8_CORE(Act, FF, W2b, FF, FF / 64)

    const int dm = ((lane >> 4) & 3) * 4;
    const int dn = lane & 15;
#pragma unroll
    for (int mq = 0; mq < 2; ++mq)
#pragma unroll
        for (int i = 0; i < 4; ++i)
#pragma unroll
            for (int nq = 0; nq < 2; ++nq)
#pragma unroll
                for (int j = 0; j < 2; ++j) {
                    int rowb = m0 + wr * 128 + mq * 64 + i * 16 + dm;
                    int col = n0 + wc * 64 + nq * 32 + j * 16 + dn;
                    f32x4 v = acc[mq][i][nq][j];
#pragma unroll
                    for (int r = 0; r < 4; ++r)
                        Out[(size_t)(rowb + r) * HH + col] = v[r];
                }
}

extern "C" void kernel_launch(void* const* d_in, const int* in_sizes, int n_in,
                              void* d_out, int out_size, void* d_ws, size_t ws_size,
                              hipStream_t stream) {
    const float* x  = (const float*)d_in[0];
    const float* w1 = (const float*)d_in[1];
    const float* v1 = (const float*)d_in[2];
    const float* w2 = (const float*)d_in[3];
    float* out = (float*)d_out;

    unsigned short* xb   = (unsigned short*)d_ws;               // [T][H]
    unsigned short* wcat = xb + (size_t)TT * HH;                // [2F][H]
    unsigned short* w2b  = wcat + (size_t)NCAT * HH;            // [H][F]
    unsigned short* act  = w2b + (size_t)HH * FF;               // [T][F]

    hipFuncSetAttribute((const void*)gemm_swiglu,
                        hipFuncAttributeMaxDynamicSharedMemorySize, 131072);
    hipFuncSetAttribute((const void*)gemm_down,
                        hipFuncAttributeMaxDynamicSharedMemorySize, 131072);

    cvt_lin<<<2048, 256, 0, stream>>>(x, xb, (long)TT * HH / 4);
    cvt_lin<<<2048, 256, 0, stream>>>(w2, w2b, (long)HH * FF / 4);
    cvt_tri<<<(HH / 64) * (FF / 64), 256, 0, stream>>>(w1, wcat, 0);
    cvt_tri<<<(HH / 64) * (FF / 64), 256, 0, stream>>>(v1, wcat, 16);

    gemm_swiglu<<<(TT / 256) * (NCAT / 256), 512, 131072, stream>>>(xb, wcat, act);
    gemm_down<<<(TT / 256) * (HH / 256), 512, 131072, stream>>>(act, w2b, out);
}